// Round 2
// baseline (150.321 us; speedup 1.0000x reference)
//
#include <hip/hip_runtime.h>

// CommSlave — Round 10: 16-row waves for 2x residency.
// r9 was fully resident at 8 blocks/CU (grid 2048 == LDS cap) = 2 waves/SIMD,
// ~85% stall on dependent chains. This round halves the wave tile to 16 rows
// (1 m-tile): grid 4096 = 16 blocks/CU = 4 waves/SIMD; LDS 17920 -> 8960 B.
// Same per-row math, double the latency-hiding concurrency. Attention is
// re-laned as 4 lanes/row x 16 rows. Still barrier-free (wave-local LDS).
// Fragment maps (verified r4-r7): A[m=lane&15][k=quad*8+j]; C/D col=lane&15,
// row=quad*4+reg. B-frag chunk layout: element lane*8+j = B[k=ks*32+quad*8+j][n].

#define NACT 14
#define BTOT 65536

typedef unsigned int  u32;
typedef unsigned short u16;
using short8 = __attribute__((ext_vector_type(8))) short;
using f32x4  = __attribute__((ext_vector_type(4))) float;

// frag-order image offsets (u16 units); each frag = 512 u16 = 1 KB
#define ENC0 0        // 32 frags: f = ks*4 + t        (ks<8, t<4)
#define WIH0 16384    // 24 frags: f = (u*3+g)*2 + ks  (u<4, g<3, ks<2)
#define WHH0 28672    // 24 frags: same
#define QKV0 40960    // 12 frags: f = t*2 + ks        (t<6: q0,q1,k0,k1,v0,v1)
#define DEC0 47104    //  3 frags: f = ks              (ks<3)
#define WTOT 48640

__device__ u16   g_wbuf[WTOT];
__device__ float g_bias[256];   // r: bih+bhh, z: bih+bhh, n_i: bih, n_h: bhh

__device__ __forceinline__ u32 f2bf_rne(float f){
  u32 x = __float_as_uint(f);
  return (x + 0x7fffu + ((x >> 16) & 1u)) >> 16;
}
__device__ __forceinline__ u32 pk2(float a, float b){
  u32 d;
  asm("v_cvt_pk_bf16_f32 %0, %1, %2" : "=v"(d) : "v"(a), "v"(b));
  return d;
}
__device__ __forceinline__ float blo(u32 u){ return __uint_as_float(u << 16); }
__device__ __forceinline__ float bhi(u32 u){ return __uint_as_float(u & 0xffff0000u); }
__device__ __forceinline__ float sigm(float x){ return 1.0f / (1.0f + __expf(-x)); }
__device__ __forceinline__ float tanhp(float x){ return 1.0f - 2.0f / (__expf(2.0f * x) + 1.0f); }
__device__ __forceinline__ short8 as_s8(uint4 v){ union { uint4 u; short8 s; } x; x.u = v; return x.s; }

#define MFMA16(a,b,c) __builtin_amdgcn_mfma_f32_16x16x32_bf16((a),(b),(c),0,0,0)

// ======================= prep: build frag-order bf16 images ==================
__global__ void prep(const float* __restrict__ encW, const float* __restrict__ Wih,
                     const float* __restrict__ Whh,  const float* __restrict__ qW,
                     const float* __restrict__ kW,   const float* __restrict__ vW,
                     const float* __restrict__ decW, const float* __restrict__ bih,
                     const float* __restrict__ bhh)
{
  int j = blockIdx.x * 256 + threadIdx.x;
  if (blockIdx.x == 0) {
    int n = threadIdx.x & 63, g = threadIdx.x >> 6;
    float v;
    if      (g == 0) v = bih[n]       + bhh[n];
    else if (g == 1) v = bih[64 + n]  + bhh[64 + n];
    else if (g == 2) v = bih[128 + n];
    else             v = bhh[128 + n];
    g_bias[threadIdx.x] = v;
  }
  if (j >= WTOT) return;
  int pos  = j & 511;
  int lane = pos >> 3, jj = pos & 7;
  int quad = lane >> 4, l16 = lane & 15;
  float val = 0.f;
  if (j < WIH0) {                         // ENC
    int f = j >> 9, ks = f >> 2, t = f & 3;
    int k = ks * 32 + quad * 8 + jj, n = 16 * t + l16;
    val = encW[k * 64 + n];
  } else if (j < WHH0) {                  // WIH
    int f = (j - WIH0) >> 9;
    int u = f / 6, g = (f >> 1) % 3, ks = f & 1;
    int wrow = 64 * g + 16 * u + l16, k = ks * 32 + quad * 8 + jj;
    val = Wih[wrow * 64 + k];
  } else if (j < QKV0) {                  // WHH
    int f = (j - WHH0) >> 9;
    int u = f / 6, g = (f >> 1) % 3, ks = f & 1;
    int wrow = 64 * g + 16 * u + l16, k = ks * 32 + quad * 8 + jj;
    val = Whh[wrow * 64 + k];
  } else if (j < DEC0) {                  // QKV
    int f = (j - QKV0) >> 9, t = f >> 1, ks = f & 1;
    int n = 16 * t + l16, mtx = n >> 5, nn = n & 31;
    int k = ks * 32 + quad * 8 + jj;
    val = (mtx == 0) ? qW[k * 32 + nn] * 0.17677669529663687f
        : (mtx == 1) ? kW[k * 32 + nn] : vW[k * 32 + nn];
  } else {                                // DEC
    int f = (j - DEC0) >> 9;
    int k = f * 32 + quad * 8 + jj, n = l16;
    if (n < 14) val = decW[k * 14 + n];
  }
  g_wbuf[j] = (u16)f2bf_rne(val);
}

// ======================= main ================================================
// LDS/block (8960 B): X bf16 [16][72] @u16 0   (x; post-GRU: cols 32-63 v,
// cols 0-31 xatt); H bf16 [16][72] @u16 1152 (hid -> h_out, direct writes);
// Sf fp32 [16][68] @u16 2304 (q cols 0-31, k cols 32-63; p overwrites q 0-7).
// One 64-thr wave per block, 16 rows; no barriers (wave-local LDS only).
__global__ __launch_bounds__(64, 4)
void commslave_main(const float* __restrict__ obs,  const float* __restrict__ hid,
                    const float* __restrict__ encb, const float* __restrict__ vb,
                    const float* __restrict__ decb, float* __restrict__ out)
{
  __shared__ __align__(16) u16 ldsU[4480];

  const int lane = threadIdx.x & 63;
  const int quad = lane >> 4;
  const int l16  = lane & 15;
  const int gr   = blockIdx.x * 16;
  float* Sf = (float*)(ldsU + 2304);

  // ---- issue hid loads (rows gr..gr+15) + first obs prefetch slots ----
  float4 hv[4];
  #pragma unroll
  for (int i = 0; i < 4; i++) {
    int c = lane + 64 * i;
    hv[i] = ((const float4*)hid)[(size_t)(gr + (c >> 4)) * 16 + (c & 15)];
  }
  float4 pre[2][2];             // [ks&1][half] — static under full unroll
  {
    const float* ap = obs + (size_t)(gr + l16) * 256 + quad * 8;
    pre[0][0] = *(const float4*)ap;        pre[0][1] = *(const float4*)(ap + 4);
    pre[1][0] = *(const float4*)(ap + 32); pre[1][1] = *(const float4*)(ap + 36);
  }

  // ---- stage hid -> H bf16 (obs loads stay in flight) ----
  #pragma unroll
  for (int i = 0; i < 4; i++) {
    int c = lane + 64 * i;
    int lr = c >> 4, c4 = c & 15;
    *(uint2*)&ldsU[1152 + lr * 72 + c4 * 4] =
        make_uint2(pk2(hv[i].x, hv[i].y), pk2(hv[i].z, hv[i].w));
  }

  // ---- enc: x = relu(obs @ encW + encb), depth-2 obs prefetch ----
  f32x4 ce[4];
  #pragma unroll
  for (int t = 0; t < 4; t++) {
    float bv = encb[16 * t + l16];
    ce[t] = (f32x4){bv, bv, bv, bv};
  }
  #pragma unroll
  for (int ks = 0; ks < 8; ks++) {
    const int s = ks & 1;
    float4 a0 = pre[s][0], a1 = pre[s][1];
    short8 a = as_s8(make_uint4(pk2(a0.x, a0.y), pk2(a0.z, a0.w), pk2(a1.x, a1.y), pk2(a1.z, a1.w)));
    if (ks < 6) {
      const float* ap = obs + (size_t)(gr + l16) * 256 + (ks + 2) * 32 + quad * 8;
      pre[s][0] = *(const float4*)ap;
      pre[s][1] = *(const float4*)(ap + 4);
    }
    #pragma unroll
    for (int t = 0; t < 4; t++) {
      short8 b = as_s8(*(const uint4*)&g_wbuf[ENC0 + (ks * 4 + t) * 512 + lane * 8]);
      ce[t] = MFMA16(a, b, ce[t]);
    }
  }
  // direct bf16 C-layout store of x -> X (row = quad*4+r, col = 16t+l16)
  #pragma unroll
  for (int t = 0; t < 4; t++)
    #pragma unroll
    for (int r = 0; r < 4; r++) {
      float xv = fmaxf(ce[t][r], 0.f);
      ldsU[(quad * 4 + r) * 72 + 16 * t + l16] = (u16)pk2(xv, xv);
    }

  // ---- GRU ----
  short8 ax[2], ah[2];
  #pragma unroll
  for (int ks = 0; ks < 2; ks++) {
    ax[ks] = *(const short8*)&ldsU[l16 * 72 + ks * 32 + quad * 8];
    ah[ks] = *(const short8*)&ldsU[1152 + l16 * 72 + ks * 32 + quad * 8];
  }
  #pragma unroll 1
  for (int u = 0; u < 4; u++) {
    f32x4 g6[6];
    #pragma unroll
    for (int t = 0; t < 6; t++) g6[t] = (f32x4){0.f, 0.f, 0.f, 0.f};
    #pragma unroll
    for (int g = 0; g < 3; g++) {
      #pragma unroll
      for (int ks = 0; ks < 2; ks++) {
        int f = (u * 3 + g) * 2 + ks;
        short8 bi = as_s8(*(const uint4*)&g_wbuf[WIH0 + f * 512 + lane * 8]);
        short8 bh = as_s8(*(const uint4*)&g_wbuf[WHH0 + f * 512 + lane * 8]);
        g6[g]     = MFMA16(ax[ks], bi, g6[g]);
        g6[3 + g] = MFMA16(ah[ks], bh, g6[3 + g]);
      }
    }
    int nc = 16 * u + l16;
    float brz = g_bias[nc], bzz = g_bias[64 + nc], bni = g_bias[128 + nc], bnh = g_bias[192 + nc];
    // read hp (original hid bf16) BEFORE overwriting H with h_out
    float hp[4];
    #pragma unroll
    for (int r = 0; r < 4; r++)
      hp[r] = blo(ldsU[1152 + (quad * 4 + r) * 72 + nc]);
    #pragma unroll
    for (int r = 0; r < 4; r++) {
      float rg = sigm(g6[0][r] + g6[3][r] + brz);
      float zg = sigm(g6[1][r] + g6[4][r] + bzz);
      float nn = tanhp(g6[2][r] + bni + rg * (g6[5][r] + bnh));
      float ho = (1.f - zg) * nn + zg * hp[r];
      ldsU[1152 + (quad * 4 + r) * 72 + nc] = (u16)pk2(ho, ho);   // h_out -> H
    }
  }

  // ---- q,k,v ----
  short8 hx[2];
  #pragma unroll
  for (int ks = 0; ks < 2; ks++)
    hx[ks] = *(const short8*)&ldsU[1152 + l16 * 72 + ks * 32 + quad * 8];
  f32x4 cq[6];
  #pragma unroll
  for (int t = 0; t < 6; t++) {
    float bv = (t >= 4) ? vb[16 * (t - 4) + l16] : 0.f;
    cq[t] = (f32x4){bv, bv, bv, bv};
  }
  #pragma unroll
  for (int ks = 0; ks < 2; ks++)
    #pragma unroll
    for (int t = 0; t < 6; t++) {
      short8 b = as_s8(*(const uint4*)&g_wbuf[QKV0 + (t * 2 + ks) * 512 + lane * 8]);
      cq[t] = MFMA16(hx[ks], b, cq[t]);
    }
  #pragma unroll
  for (int t = 0; t < 4; t++)                 // q cols 0-31, k cols 32-63 (fp32)
    #pragma unroll
    for (int r = 0; r < 4; r++)
      Sf[(quad * 4 + r) * 68 + 16 * t + l16] = cq[t][r];
  #pragma unroll
  for (int t = 4; t < 6; t++)                 // v -> X cols 32-63 (bf16)
    #pragma unroll
    for (int r = 0; r < 4; r++)
      ldsU[(quad * 4 + r) * 72 + 32 + 16 * (t - 4) + l16] =
          (u16)pk2(fmaxf(cq[t][r], 0.f), 0.f);

  // ---- attention (4 lanes per row, 16 rows) ----
  {
    const int r_l = lane >> 2, s4 = lane & 3;
    const int gb = r_l & ~7, ri = r_l & 7;
    const float* fq = &Sf[r_l * 68];
    float sc[2];
    #pragma unroll
    for (int jj = 0; jj < 2; jj++) {
      int j = 2 * s4 + jj;
      const float* fk = &Sf[(gb + j) * 68 + 32];
      float d = 0.f;
      #pragma unroll
      for (int a4 = 0; a4 < 32; a4 += 4) {
        float4 q4 = *(const float4*)&fq[a4];
        float4 k4 = *(const float4*)&fk[a4];
        d += q4.x * k4.x + q4.y * k4.y + q4.z * k4.z + q4.w * k4.w;
      }
      sc[jj] = (j == ri) ? -1e30f : d;
    }
    float m = fmaxf(sc[0], sc[1]);
    m = fmaxf(m, __shfl_xor(m, 1));
    m = fmaxf(m, __shfl_xor(m, 2));
    float p[2], sum = 0.f;
    #pragma unroll
    for (int jj = 0; jj < 2; jj++) {
      int j = 2 * s4 + jj;
      p[jj] = (j == ri) ? 0.f : __expf(sc[jj] - m);
      sum += p[jj];
    }
    sum += __shfl_xor(sum, 1);
    sum += __shfl_xor(sum, 2);
    float inv = 1.f / sum;
    #pragma unroll
    for (int jj = 0; jj < 2; jj++)
      Sf[r_l * 68 + 2 * s4 + jj] = p[jj] * inv;
    // PV: each lane owns cols 8*s4 .. 8*s4+7
    float xa[8];
    #pragma unroll
    for (int u = 0; u < 8; u++) xa[u] = 0.f;
    #pragma unroll
    for (int j = 0; j < 8; j++) {
      float aj = Sf[r_l * 68 + j];
      const u16* vp = &ldsU[(gb + j) * 72 + 32 + 8 * s4];
      uint4 v0 = *(const uint4*)vp;
      xa[0] += aj * blo(v0.x); xa[1] += aj * bhi(v0.x);
      xa[2] += aj * blo(v0.y); xa[3] += aj * bhi(v0.y);
      xa[4] += aj * blo(v0.z); xa[5] += aj * bhi(v0.z);
      xa[6] += aj * blo(v0.w); xa[7] += aj * bhi(v0.w);
    }
    u16* xp = &ldsU[r_l * 72 + 8 * s4];
    *(uint4*)xp = make_uint4(pk2(xa[0], xa[1]), pk2(xa[2], xa[3]),
                             pk2(xa[4], xa[5]), pk2(xa[6], xa[7]));
  }

  // ---- dec: [h_out | xatt] @ decW + decb ----
  {
    float db = (l16 < NACT) ? decb[l16] : 0.f;
    f32x4 co = (f32x4){db, db, db, db};
    #pragma unroll
    for (int ks = 0; ks < 2; ks++) {
      short8 b = as_s8(*(const uint4*)&g_wbuf[DEC0 + ks * 512 + lane * 8]);
      short8 a = *(const short8*)&ldsU[1152 + l16 * 72 + ks * 32 + quad * 8];
      co = MFMA16(a, b, co);
    }
    short8 b2 = as_s8(*(const uint4*)&g_wbuf[DEC0 + 2 * 512 + lane * 8]);
    short8 a2 = *(const short8*)&ldsU[l16 * 72 + quad * 8];
    co = MFMA16(a2, b2, co);
    if (l16 < NACT)
      #pragma unroll
      for (int r = 0; r < 4; r++)
        out[(size_t)(gr + quad * 4 + r) * NACT + l16] = co[r];
  }

  // ---- h_out fp32 global store (from H bf16) ----
  {
    float* outH = out + (size_t)BTOT * NACT;
    #pragma unroll
    for (int i = 0; i < 2; i++) {
      int c = lane + 64 * i, lr = c >> 3, j = c & 7;
      uint4 u = *(const uint4*)&ldsU[1152 + lr * 72 + 8 * j];
      *(float4*)(outH + (size_t)(gr + lr) * 64 + 8 * j) =
          make_float4(blo(u.x), bhi(u.x), blo(u.y), bhi(u.y));
      *(float4*)(outH + (size_t)(gr + lr) * 64 + 8 * j + 4) =
          make_float4(blo(u.z), bhi(u.z), blo(u.w), bhi(u.w));
    }
  }
}

extern "C" void kernel_launch(void* const* d_in, const int* in_sizes, int n_in,
                              void* d_out, int out_size, void* d_ws, size_t ws_size,
                              hipStream_t stream) {
  (void)in_sizes; (void)n_in; (void)d_ws; (void)ws_size; (void)out_size;
  const float* obs  = (const float*)d_in[0];
  const float* hid  = (const float*)d_in[1];
  const float* encW = (const float*)d_in[2];
  const float* encb = (const float*)d_in[3];
  const float* Wih  = (const float*)d_in[4];
  const float* Whh  = (const float*)d_in[5];
  const float* bih  = (const float*)d_in[6];
  const float* bhh  = (const float*)d_in[7];
  const float* qW   = (const float*)d_in[8];
  const float* kW   = (const float*)d_in[9];
  const float* vW   = (const float*)d_in[10];
  const float* vb   = (const float*)d_in[11];
  const float* decW = (const float*)d_in[12];
  const float* decb = (const float*)d_in[13];
  float* out = (float*)d_out;

  prep<<<(WTOT + 255) / 256, 256, 0, stream>>>(encW, Wih, Whh, qW, kW, vW, decW, bih, bhh);
  commslave_main<<<BTOT / 16, 64, 0, stream>>>(obs, hid, encb, vb, decb, out);
}

// Round 3
// 147.483 us; speedup vs baseline: 1.0192x; 1.0192x over previous
//
#include <hip/hip_runtime.h>

// CommSlave — Round 11: persistent 8-wave blocks, weights staged in LDS.
// r9/r10 post-mortem: runtime pinned at 42 µs independent of residency ->
// phase-locked waves all stalling on the same L2 frag-load chains; per-CU
// L1 port carries 16 waves x ~95 KB of *identical* weight fragments.
// This round: grid 256 = 1 block/CU, 512 thr = 8 waves x 16 rows, 2 chunks
// per block. WIH/WHH/QKV/DEC frags (63 KB) + bias (1 KB) staged into LDS
// once (single barrier), then read via ds_read_b128 (~120cy latency vs
// ~300+ L2). ENC frags stay L2-streamed (overlap the HBM obs phase).
// Chunk-1 obs prefetch issues during chunk-0 enc tail -> HBM continuity.
// LDS 139264 B. Fragment maps (verified r4-r7): A[m=lane&15][k=quad*8+j];
// C/D col=lane&15, row=quad*4+reg; B-frag elem lane*8+j = B[k=ks*32+quad*8+j][n].

#define NACT 14
#define BTOT 65536

typedef unsigned int  u32;
typedef unsigned short u16;
using short8 = __attribute__((ext_vector_type(8))) short;
using f32x4  = __attribute__((ext_vector_type(4))) float;

// global frag-order image offsets (u16 units); each frag = 512 u16 = 1 KB
#define ENC0 0        // 32 frags: f = ks*4 + t        (ks<8, t<4)
#define WIH0 16384    // 24 frags: f = (u*3+g)*2 + ks  (u<4, g<3, ks<2)
#define WHH0 28672    // 24 frags: same
#define QKV0 40960    // 12 frags: f = t*2 + ks        (t<6: q0,q1,k0,k1,v0,v1)
#define DEC0 47104    //  3 frags: f = ks              (ks<3)
#define WTOT 48640

// staged-weight u16 offsets within LDS (same order as g_wbuf[WIH0..])
#define WIHL 0
#define WHHL 12288
#define QKVL 24576
#define DECL 30720
#define DATA0 32256   // per-wave data base = DATA0 + w*4608 (u16)
#define BIASL 69120   // f32[256] at u16 69120
#define LDSU16 69632  // 139264 B total

__device__ __align__(16) u16   g_wbuf[WTOT];
__device__ __align__(16) float g_bias[256];   // r: bih+bhh, z: bih+bhh, n_i: bih, n_h: bhh

__device__ __forceinline__ u32 f2bf_rne(float f){
  u32 x = __float_as_uint(f);
  return (x + 0x7fffu + ((x >> 16) & 1u)) >> 16;
}
__device__ __forceinline__ u32 pk2(float a, float b){
  u32 d;
  asm("v_cvt_pk_bf16_f32 %0, %1, %2" : "=v"(d) : "v"(a), "v"(b));
  return d;
}
__device__ __forceinline__ float blo(u32 u){ return __uint_as_float(u << 16); }
__device__ __forceinline__ float bhi(u32 u){ return __uint_as_float(u & 0xffff0000u); }
__device__ __forceinline__ float sigm(float x){ return 1.0f / (1.0f + __expf(-x)); }
__device__ __forceinline__ float tanhp(float x){ return 1.0f - 2.0f / (__expf(2.0f * x) + 1.0f); }
__device__ __forceinline__ short8 as_s8(uint4 v){ union { uint4 u; short8 s; } x; x.u = v; return x.s; }

#define MFMA16(a,b,c) __builtin_amdgcn_mfma_f32_16x16x32_bf16((a),(b),(c),0,0,0)

// ======================= prep: build frag-order bf16 images ==================
__global__ void prep(const float* __restrict__ encW, const float* __restrict__ Wih,
                     const float* __restrict__ Whh,  const float* __restrict__ qW,
                     const float* __restrict__ kW,   const float* __restrict__ vW,
                     const float* __restrict__ decW, const float* __restrict__ bih,
                     const float* __restrict__ bhh)
{
  int j = blockIdx.x * 256 + threadIdx.x;
  if (blockIdx.x == 0) {
    int n = threadIdx.x & 63, g = threadIdx.x >> 6;
    float v;
    if      (g == 0) v = bih[n]       + bhh[n];
    else if (g == 1) v = bih[64 + n]  + bhh[64 + n];
    else if (g == 2) v = bih[128 + n];
    else             v = bhh[128 + n];
    g_bias[threadIdx.x] = v;
  }
  if (j >= WTOT) return;
  int pos  = j & 511;
  int lane = pos >> 3, jj = pos & 7;
  int quad = lane >> 4, l16 = lane & 15;
  float val = 0.f;
  if (j < WIH0) {                         // ENC
    int f = j >> 9, ks = f >> 2, t = f & 3;
    int k = ks * 32 + quad * 8 + jj, n = 16 * t + l16;
    val = encW[k * 64 + n];
  } else if (j < WHH0) {                  // WIH
    int f = (j - WIH0) >> 9;
    int u = f / 6, g = (f >> 1) % 3, ks = f & 1;
    int wrow = 64 * g + 16 * u + l16, k = ks * 32 + quad * 8 + jj;
    val = Wih[wrow * 64 + k];
  } else if (j < QKV0) {                  // WHH
    int f = (j - WHH0) >> 9;
    int u = f / 6, g = (f >> 1) % 3, ks = f & 1;
    int wrow = 64 * g + 16 * u + l16, k = ks * 32 + quad * 8 + jj;
    val = Whh[wrow * 64 + k];
  } else if (j < DEC0) {                  // QKV
    int f = (j - QKV0) >> 9, t = f >> 1, ks = f & 1;
    int n = 16 * t + l16, mtx = n >> 5, nn = n & 31;
    int k = ks * 32 + quad * 8 + jj;
    val = (mtx == 0) ? qW[k * 32 + nn] * 0.17677669529663687f
        : (mtx == 1) ? kW[k * 32 + nn] : vW[k * 32 + nn];
  } else {                                // DEC
    int f = (j - DEC0) >> 9;
    int k = f * 32 + quad * 8 + jj, n = l16;
    if (n < 14) val = decW[k * 14 + n];
  }
  g_wbuf[j] = (u16)f2bf_rne(val);
}

// ======================= per-chunk body ======================================
// Per-wave data (u16 offsets from Xb): X bf16 [16][72] @0 (x; post-GRU cols
// 32-63 v, 0-31 xatt); H bf16 [16][72] @1152 (hid -> h_out); Sf fp32 [16][68]
// @2304 (q 0-31, k 32-63; p overwrites q 0-7). Wave-local => barrier-free.
template<bool LAST>
__device__ __forceinline__ void tile_body(
    int gr, int grN,
    u16* __restrict__ Xb, const u16* __restrict__ wl, const float* __restrict__ biasL,
    const float* __restrict__ obs, const float* __restrict__ hid,
    const float* __restrict__ encb, const float* __restrict__ vb,
    const float* __restrict__ decb, float* __restrict__ out,
    float4 (&pre)[2][2], float4 (&preN)[2][2],
    int lane, int quad, int l16)
{
  u16*   Hb = Xb + 1152;
  float* Sf = (float*)(Xb + 2304);

  // ---- hid loads (rows gr..gr+15) ----
  float4 hv[4];
  #pragma unroll
  for (int i = 0; i < 4; i++) {
    int c = lane + 64 * i;
    hv[i] = ((const float4*)hid)[(size_t)(gr + (c >> 4)) * 16 + (c & 15)];
  }
  #pragma unroll
  for (int i = 0; i < 4; i++) {
    int c = lane + 64 * i;
    int lr = c >> 4, c4 = c & 15;
    *(uint2*)&Hb[lr * 72 + c4 * 4] = make_uint2(pk2(hv[i].x, hv[i].y), pk2(hv[i].z, hv[i].w));
  }

  // ---- enc: x = relu(obs @ encW + encb), depth-2 obs prefetch ----
  f32x4 ce[4];
  #pragma unroll
  for (int t = 0; t < 4; t++) {
    float bv = encb[16 * t + l16];
    ce[t] = (f32x4){bv, bv, bv, bv};
  }
  #pragma unroll
  for (int ks = 0; ks < 8; ks++) {
    const int s = ks & 1;
    float4 a0 = pre[s][0], a1 = pre[s][1];
    short8 a = as_s8(make_uint4(pk2(a0.x, a0.y), pk2(a0.z, a0.w), pk2(a1.x, a1.y), pk2(a1.z, a1.w)));
    if (ks < 6) {
      const float* ap = obs + (size_t)(gr + l16) * 256 + (ks + 2) * 32 + quad * 8;
      pre[s][0] = *(const float4*)ap;
      pre[s][1] = *(const float4*)(ap + 4);
    }
    #pragma unroll
    for (int t = 0; t < 4; t++) {
      short8 b = as_s8(*(const uint4*)&g_wbuf[ENC0 + (ks * 4 + t) * 512 + lane * 8]);
      ce[t] = MFMA16(a, b, ce[t]);
    }
  }
  // issue NEXT chunk's first obs slots: in flight through GRU/attn/dec
  if (!LAST) {
    const float* ap = obs + (size_t)(grN + l16) * 256 + quad * 8;
    preN[0][0] = *(const float4*)ap;        preN[0][1] = *(const float4*)(ap + 4);
    preN[1][0] = *(const float4*)(ap + 32); preN[1][1] = *(const float4*)(ap + 36);
  }
  // direct bf16 C-layout store of x -> X (row = quad*4+r, col = 16t+l16)
  #pragma unroll
  for (int t = 0; t < 4; t++)
    #pragma unroll
    for (int r = 0; r < 4; r++) {
      float xv = fmaxf(ce[t][r], 0.f);
      Xb[(quad * 4 + r) * 72 + 16 * t + l16] = (u16)pk2(xv, xv);
    }

  // ---- GRU (frags from LDS) ----
  short8 ax[2], ah[2];
  #pragma unroll
  for (int ks = 0; ks < 2; ks++) {
    ax[ks] = *(const short8*)&Xb[l16 * 72 + ks * 32 + quad * 8];
    ah[ks] = *(const short8*)&Hb[l16 * 72 + ks * 32 + quad * 8];
  }
  #pragma unroll
  for (int u = 0; u < 4; u++) {
    f32x4 g6[6];
    #pragma unroll
    for (int t = 0; t < 6; t++) g6[t] = (f32x4){0.f, 0.f, 0.f, 0.f};
    #pragma unroll
    for (int g = 0; g < 3; g++) {
      #pragma unroll
      for (int ks = 0; ks < 2; ks++) {
        int f = (u * 3 + g) * 2 + ks;
        short8 bi = *(const short8*)&wl[WIHL + f * 512 + lane * 8];
        short8 bh = *(const short8*)&wl[WHHL + f * 512 + lane * 8];
        g6[g]     = MFMA16(ax[ks], bi, g6[g]);
        g6[3 + g] = MFMA16(ah[ks], bh, g6[3 + g]);
      }
    }
    int nc = 16 * u + l16;
    float brz = biasL[nc], bzz = biasL[64 + nc], bni = biasL[128 + nc], bnh = biasL[192 + nc];
    // read hp (original hid bf16) BEFORE overwriting H with h_out
    float hp[4];
    #pragma unroll
    for (int r = 0; r < 4; r++)
      hp[r] = blo(Hb[(quad * 4 + r) * 72 + nc]);
    #pragma unroll
    for (int r = 0; r < 4; r++) {
      float rg = sigm(g6[0][r] + g6[3][r] + brz);
      float zg = sigm(g6[1][r] + g6[4][r] + bzz);
      float nn = tanhp(g6[2][r] + bni + rg * (g6[5][r] + bnh));
      float ho = (1.f - zg) * nn + zg * hp[r];
      Hb[(quad * 4 + r) * 72 + nc] = (u16)pk2(ho, ho);   // h_out -> H
    }
  }

  // ---- q,k,v (frags from LDS) ----
  short8 hx[2];
  #pragma unroll
  for (int ks = 0; ks < 2; ks++)
    hx[ks] = *(const short8*)&Hb[l16 * 72 + ks * 32 + quad * 8];
  f32x4 cq[6];
  #pragma unroll
  for (int t = 0; t < 6; t++) {
    float bv = (t >= 4) ? vb[16 * (t - 4) + l16] : 0.f;
    cq[t] = (f32x4){bv, bv, bv, bv};
  }
  #pragma unroll
  for (int ks = 0; ks < 2; ks++)
    #pragma unroll
    for (int t = 0; t < 6; t++) {
      short8 b = *(const short8*)&wl[QKVL + (t * 2 + ks) * 512 + lane * 8];
      cq[t] = MFMA16(hx[ks], b, cq[t]);
    }
  #pragma unroll
  for (int t = 0; t < 4; t++)                 // q cols 0-31, k cols 32-63 (fp32)
    #pragma unroll
    for (int r = 0; r < 4; r++)
      Sf[(quad * 4 + r) * 68 + 16 * t + l16] = cq[t][r];
  #pragma unroll
  for (int t = 4; t < 6; t++)                 // v -> X cols 32-63 (bf16)
    #pragma unroll
    for (int r = 0; r < 4; r++)
      Xb[(quad * 4 + r) * 72 + 32 + 16 * (t - 4) + l16] =
          (u16)pk2(fmaxf(cq[t][r], 0.f), 0.f);

  // ---- attention (4 lanes per row, 16 rows) ----
  {
    const int r_l = lane >> 2, s4 = lane & 3;
    const int gb = r_l & ~7, ri = r_l & 7;
    const float* fq = &Sf[r_l * 68];
    float sc[2];
    #pragma unroll
    for (int jj = 0; jj < 2; jj++) {
      int j = 2 * s4 + jj;
      const float* fk = &Sf[(gb + j) * 68 + 32];
      float d = 0.f;
      #pragma unroll
      for (int a4 = 0; a4 < 32; a4 += 4) {
        float4 q4 = *(const float4*)&fq[a4];
        float4 k4 = *(const float4*)&fk[a4];
        d += q4.x * k4.x + q4.y * k4.y + q4.z * k4.z + q4.w * k4.w;
      }
      sc[jj] = (j == ri) ? -1e30f : d;
    }
    float m = fmaxf(sc[0], sc[1]);
    m = fmaxf(m, __shfl_xor(m, 1));
    m = fmaxf(m, __shfl_xor(m, 2));
    float p[2], sum = 0.f;
    #pragma unroll
    for (int jj = 0; jj < 2; jj++) {
      int j = 2 * s4 + jj;
      p[jj] = (j == ri) ? 0.f : __expf(sc[jj] - m);
      sum += p[jj];
    }
    sum += __shfl_xor(sum, 1);
    sum += __shfl_xor(sum, 2);
    float inv = 1.f / sum;
    #pragma unroll
    for (int jj = 0; jj < 2; jj++)
      Sf[r_l * 68 + 2 * s4 + jj] = p[jj] * inv;
    // PV: each lane owns cols 8*s4 .. 8*s4+7
    float xa[8];
    #pragma unroll
    for (int u = 0; u < 8; u++) xa[u] = 0.f;
    #pragma unroll
    for (int j = 0; j < 8; j++) {
      float aj = Sf[r_l * 68 + j];
      const u16* vp = &Xb[(gb + j) * 72 + 32 + 8 * s4];
      uint4 v0 = *(const uint4*)vp;
      xa[0] += aj * blo(v0.x); xa[1] += aj * bhi(v0.x);
      xa[2] += aj * blo(v0.y); xa[3] += aj * bhi(v0.y);
      xa[4] += aj * blo(v0.z); xa[5] += aj * bhi(v0.z);
      xa[6] += aj * blo(v0.w); xa[7] += aj * bhi(v0.w);
    }
    u16* xp = &Xb[r_l * 72 + 8 * s4];
    *(uint4*)xp = make_uint4(pk2(xa[0], xa[1]), pk2(xa[2], xa[3]),
                             pk2(xa[4], xa[5]), pk2(xa[6], xa[7]));
  }

  // ---- dec: [h_out | xatt] @ decW + decb ----
  {
    float db = (l16 < NACT) ? decb[l16] : 0.f;
    f32x4 co = (f32x4){db, db, db, db};
    #pragma unroll
    for (int ks = 0; ks < 2; ks++) {
      short8 b = *(const short8*)&wl[DECL + ks * 512 + lane * 8];
      short8 a = *(const short8*)&Hb[l16 * 72 + ks * 32 + quad * 8];
      co = MFMA16(a, b, co);
    }
    short8 b2 = *(const short8*)&wl[DECL + 2 * 512 + lane * 8];
    short8 a2 = *(const short8*)&Xb[l16 * 72 + quad * 8];
    co = MFMA16(a2, b2, co);
    if (l16 < NACT)
      #pragma unroll
      for (int r = 0; r < 4; r++)
        out[(size_t)(gr + quad * 4 + r) * NACT + l16] = co[r];
  }

  // ---- h_out fp32 global store (from H bf16) ----
  {
    float* outH = out + (size_t)BTOT * NACT;
    #pragma unroll
    for (int i = 0; i < 2; i++) {
      int c = lane + 64 * i, lr = c >> 3, j = c & 7;
      uint4 u = *(const uint4*)&Hb[lr * 72 + 8 * j];
      *(float4*)(outH + (size_t)(gr + lr) * 64 + 8 * j) =
          make_float4(blo(u.x), bhi(u.x), blo(u.y), bhi(u.y));
      *(float4*)(outH + (size_t)(gr + lr) * 64 + 8 * j + 4) =
          make_float4(blo(u.z), bhi(u.z), blo(u.w), bhi(u.w));
    }
  }
}

// ======================= main ================================================
__global__ __launch_bounds__(512, 2)
void commslave_main(const float* __restrict__ obs,  const float* __restrict__ hid,
                    const float* __restrict__ encb, const float* __restrict__ vb,
                    const float* __restrict__ decb, float* __restrict__ out)
{
  __shared__ __align__(16) u16 lds[LDSU16];

  const int tid  = threadIdx.x;
  const int w    = tid >> 6;
  const int lane = tid & 63;
  const int quad = lane >> 4;
  const int l16  = lane & 15;

  // ---- stage WIH/WHH/QKV/DEC frags (63 KB) + bias (1 KB) into LDS ----
  {
    uint4* dw = (uint4*)lds;
    const uint4* sw = (const uint4*)(g_wbuf + WIH0);   // 4032 uint4
    #pragma unroll
    for (int i = 0; i < 8; i++) {
      int idx = tid + 512 * i;
      if (idx < 4032) dw[idx] = sw[idx];
    }
    if (tid < 64) ((uint4*)(lds + BIASL))[tid] = ((const uint4*)g_bias)[tid];
  }

  const int gr0 = blockIdx.x * 256 + w * 16;
  const int gr1 = gr0 + 128;

  // first-chunk obs slots issued BEFORE the barrier (overlap staging)
  float4 pre0[2][2], pre1[2][2];
  {
    const float* ap = obs + (size_t)(gr0 + l16) * 256 + quad * 8;
    pre0[0][0] = *(const float4*)ap;        pre0[0][1] = *(const float4*)(ap + 4);
    pre0[1][0] = *(const float4*)(ap + 32); pre0[1][1] = *(const float4*)(ap + 36);
  }
  __syncthreads();   // weights/bias visible to all waves

  u16* Xb = lds + DATA0 + w * 4608;
  const float* biasL = (const float*)(lds + BIASL);

  tile_body<false>(gr0, gr1, Xb, lds, biasL, obs, hid, encb, vb, decb, out,
                   pre0, pre1, lane, quad, l16);
  tile_body<true >(gr1, 0,   Xb, lds, biasL, obs, hid, encb, vb, decb, out,
                   pre1, pre0, lane, quad, l16);
}

extern "C" void kernel_launch(void* const* d_in, const int* in_sizes, int n_in,
                              void* d_out, int out_size, void* d_ws, size_t ws_size,
                              hipStream_t stream) {
  (void)in_sizes; (void)n_in; (void)d_ws; (void)ws_size; (void)out_size;
  const float* obs  = (const float*)d_in[0];
  const float* hid  = (const float*)d_in[1];
  const float* encW = (const float*)d_in[2];
  const float* encb = (const float*)d_in[3];
  const float* Wih  = (const float*)d_in[4];
  const float* Whh  = (const float*)d_in[5];
  const float* bih  = (const float*)d_in[6];
  const float* bhh  = (const float*)d_in[7];
  const float* qW   = (const float*)d_in[8];
  const float* kW   = (const float*)d_in[9];
  const float* vW   = (const float*)d_in[10];
  const float* vb   = (const float*)d_in[11];
  const float* decW = (const float*)d_in[12];
  const float* decb = (const float*)d_in[13];
  float* out = (float*)d_out;

  prep<<<(WTOT + 255) / 256, 256, 0, stream>>>(encW, Wih, Whh, qW, kW, vW, decW, bih, bhh);
  commslave_main<<<256, 512, 0, stream>>>(obs, hid, encb, vb, decb, out);
}

// Round 4
// 144.842 us; speedup vs baseline: 1.0378x; 1.0182x over previous
//
#include <hip/hip_runtime.h>

// CommSlave — Round 12: full-chunk register prefetch.
// r11 (weights-in-LDS, persistent 8-wave blocks) broke the 42 µs plateau
// (main fell below the 41 µs harness fills). Remaining exposure: enc phase
// consumed obs through a depth-2 prefetch chain (~3 serial HBM round-trips),
// and chunk 1's obs was demand-paged inside its own enc. This round: each
// chunk's full obs (16 float4/lane) + hid (4 float4/lane) is issued as one
// 20-load burst — chunk 0 pre-barrier, chunk 1 right after chunk 0's enc
// consumes its registers (flies under GRU/attn/dec). enc becomes pure
// consume-with-vmcnt. Peak VGPR ~170 < 256 @ 2 waves/SIMD.
// LDS 139264 B. Fragment maps (verified r4-r7): A[m=lane&15][k=quad*8+j];
// C/D col=lane&15, row=quad*4+reg; B-frag elem lane*8+j = B[k=ks*32+quad*8+j][n].

#define NACT 14
#define BTOT 65536

typedef unsigned int  u32;
typedef unsigned short u16;
using short8 = __attribute__((ext_vector_type(8))) short;
using f32x4  = __attribute__((ext_vector_type(4))) float;

// global frag-order image offsets (u16 units); each frag = 512 u16 = 1 KB
#define ENC0 0        // 32 frags: f = ks*4 + t        (ks<8, t<4)
#define WIH0 16384    // 24 frags: f = (u*3+g)*2 + ks  (u<4, g<3, ks<2)
#define WHH0 28672    // 24 frags: same
#define QKV0 40960    // 12 frags: f = t*2 + ks        (t<6: q0,q1,k0,k1,v0,v1)
#define DEC0 47104    //  3 frags: f = ks              (ks<3)
#define WTOT 48640

// staged-weight u16 offsets within LDS (same order as g_wbuf[WIH0..])
#define WIHL 0
#define WHHL 12288
#define QKVL 24576
#define DECL 30720
#define DATA0 32256   // per-wave data base = DATA0 + w*4608 (u16)
#define BIASL 69120   // f32[256] at u16 69120
#define LDSU16 69632  // 139264 B total

__device__ __align__(16) u16   g_wbuf[WTOT];
__device__ __align__(16) float g_bias[256];   // r: bih+bhh, z: bih+bhh, n_i: bih, n_h: bhh

__device__ __forceinline__ u32 f2bf_rne(float f){
  u32 x = __float_as_uint(f);
  return (x + 0x7fffu + ((x >> 16) & 1u)) >> 16;
}
__device__ __forceinline__ u32 pk2(float a, float b){
  u32 d;
  asm("v_cvt_pk_bf16_f32 %0, %1, %2" : "=v"(d) : "v"(a), "v"(b));
  return d;
}
__device__ __forceinline__ float blo(u32 u){ return __uint_as_float(u << 16); }
__device__ __forceinline__ float bhi(u32 u){ return __uint_as_float(u & 0xffff0000u); }
__device__ __forceinline__ float sigm(float x){ return 1.0f / (1.0f + __expf(-x)); }
__device__ __forceinline__ float tanhp(float x){ return 1.0f - 2.0f / (__expf(2.0f * x) + 1.0f); }
__device__ __forceinline__ short8 as_s8(uint4 v){ union { uint4 u; short8 s; } x; x.u = v; return x.s; }

#define MFMA16(a,b,c) __builtin_amdgcn_mfma_f32_16x16x32_bf16((a),(b),(c),0,0,0)

// ======================= prep: build frag-order bf16 images ==================
__global__ void prep(const float* __restrict__ encW, const float* __restrict__ Wih,
                     const float* __restrict__ Whh,  const float* __restrict__ qW,
                     const float* __restrict__ kW,   const float* __restrict__ vW,
                     const float* __restrict__ decW, const float* __restrict__ bih,
                     const float* __restrict__ bhh)
{
  int j = blockIdx.x * 256 + threadIdx.x;
  if (blockIdx.x == 0) {
    int n = threadIdx.x & 63, g = threadIdx.x >> 6;
    float v;
    if      (g == 0) v = bih[n]       + bhh[n];
    else if (g == 1) v = bih[64 + n]  + bhh[64 + n];
    else if (g == 2) v = bih[128 + n];
    else             v = bhh[128 + n];
    g_bias[threadIdx.x] = v;
  }
  if (j >= WTOT) return;
  int pos  = j & 511;
  int lane = pos >> 3, jj = pos & 7;
  int quad = lane >> 4, l16 = lane & 15;
  float val = 0.f;
  if (j < WIH0) {                         // ENC
    int f = j >> 9, ks = f >> 2, t = f & 3;
    int k = ks * 32 + quad * 8 + jj, n = 16 * t + l16;
    val = encW[k * 64 + n];
  } else if (j < WHH0) {                  // WIH
    int f = (j - WIH0) >> 9;
    int u = f / 6, g = (f >> 1) % 3, ks = f & 1;
    int wrow = 64 * g + 16 * u + l16, k = ks * 32 + quad * 8 + jj;
    val = Wih[wrow * 64 + k];
  } else if (j < QKV0) {                  // WHH
    int f = (j - WHH0) >> 9;
    int u = f / 6, g = (f >> 1) % 3, ks = f & 1;
    int wrow = 64 * g + 16 * u + l16, k = ks * 32 + quad * 8 + jj;
    val = Whh[wrow * 64 + k];
  } else if (j < DEC0) {                  // QKV
    int f = (j - QKV0) >> 9, t = f >> 1, ks = f & 1;
    int n = 16 * t + l16, mtx = n >> 5, nn = n & 31;
    int k = ks * 32 + quad * 8 + jj;
    val = (mtx == 0) ? qW[k * 32 + nn] * 0.17677669529663687f
        : (mtx == 1) ? kW[k * 32 + nn] : vW[k * 32 + nn];
  } else {                                // DEC
    int f = (j - DEC0) >> 9;
    int k = f * 32 + quad * 8 + jj, n = l16;
    if (n < 14) val = decW[k * 14 + n];
  }
  g_wbuf[j] = (u16)f2bf_rne(val);
}

// ======================= chunk load burst ====================================
struct Chunk {
  float4 ob[16];   // obs row slice: [ks*2 + half], ks<8
  float4 hv[4];    // hid rows
};

__device__ __forceinline__ void issue_loads(int gr, const float* __restrict__ obs,
                                            const float* __restrict__ hid,
                                            int lane, int quad, int l16, Chunk& c)
{
  const float* ap = obs + (size_t)(gr + l16) * 256 + quad * 8;
  #pragma unroll
  for (int ks = 0; ks < 8; ks++) {
    c.ob[2 * ks]     = *(const float4*)(ap + ks * 32);
    c.ob[2 * ks + 1] = *(const float4*)(ap + ks * 32 + 4);
  }
  #pragma unroll
  for (int i = 0; i < 4; i++) {
    int cc = lane + 64 * i;
    c.hv[i] = ((const float4*)hid)[(size_t)(gr + (cc >> 4)) * 16 + (cc & 15)];
  }
}

// ======================= per-chunk body ======================================
// Per-wave data (u16 offsets from Xb): X bf16 [16][72] @0 (x; post-GRU cols
// 32-63 v, 0-31 xatt); H bf16 [16][72] @1152 (hid -> h_out); Sf fp32 [16][68]
// @2304 (q 0-31, k 32-63; p overwrites q 0-7). Wave-local => barrier-free.
template<bool LAST>
__device__ __forceinline__ void tile_body(
    int gr, int grN,
    u16* __restrict__ Xb, const u16* __restrict__ wl, const float* __restrict__ biasL,
    const float* __restrict__ obs, const float* __restrict__ hid,
    const float* __restrict__ encb, const float* __restrict__ vb,
    const float* __restrict__ decb, float* __restrict__ out,
    Chunk& cur, Chunk& nxt,
    int lane, int quad, int l16)
{
  u16*   Hb = Xb + 1152;
  float* Sf = (float*)(Xb + 2304);

  // ---- stage hid -> H bf16 (from prefetched registers) ----
  #pragma unroll
  for (int i = 0; i < 4; i++) {
    int c = lane + 64 * i;
    int lr = c >> 4, c4 = c & 15;
    *(uint2*)&Hb[lr * 72 + c4 * 4] =
        make_uint2(pk2(cur.hv[i].x, cur.hv[i].y), pk2(cur.hv[i].z, cur.hv[i].w));
  }

  // ---- enc: x = relu(obs @ encW + encb) — consume prefetched obs ----
  f32x4 ce[4];
  #pragma unroll
  for (int t = 0; t < 4; t++) {
    float bv = encb[16 * t + l16];
    ce[t] = (f32x4){bv, bv, bv, bv};
  }
  #pragma unroll
  for (int ks = 0; ks < 8; ks++) {
    float4 a0 = cur.ob[2 * ks], a1 = cur.ob[2 * ks + 1];
    short8 a = as_s8(make_uint4(pk2(a0.x, a0.y), pk2(a0.z, a0.w), pk2(a1.x, a1.y), pk2(a1.z, a1.w)));
    #pragma unroll
    for (int t = 0; t < 4; t++) {
      short8 b = as_s8(*(const uint4*)&g_wbuf[ENC0 + (ks * 4 + t) * 512 + lane * 8]);
      ce[t] = MFMA16(a, b, ce[t]);
    }
  }
  // issue NEXT chunk's full load burst: flies under GRU/attn/dec
  if (!LAST) issue_loads(grN, obs, hid, lane, quad, l16, nxt);
  // direct bf16 C-layout store of x -> X (row = quad*4+r, col = 16t+l16)
  #pragma unroll
  for (int t = 0; t < 4; t++)
    #pragma unroll
    for (int r = 0; r < 4; r++) {
      float xv = fmaxf(ce[t][r], 0.f);
      Xb[(quad * 4 + r) * 72 + 16 * t + l16] = (u16)pk2(xv, xv);
    }

  // ---- GRU (frags from LDS) ----
  short8 ax[2], ah[2];
  #pragma unroll
  for (int ks = 0; ks < 2; ks++) {
    ax[ks] = *(const short8*)&Xb[l16 * 72 + ks * 32 + quad * 8];
    ah[ks] = *(const short8*)&Hb[l16 * 72 + ks * 32 + quad * 8];
  }
  #pragma unroll
  for (int u = 0; u < 4; u++) {
    f32x4 g6[6];
    #pragma unroll
    for (int t = 0; t < 6; t++) g6[t] = (f32x4){0.f, 0.f, 0.f, 0.f};
    #pragma unroll
    for (int g = 0; g < 3; g++) {
      #pragma unroll
      for (int ks = 0; ks < 2; ks++) {
        int f = (u * 3 + g) * 2 + ks;
        short8 bi = *(const short8*)&wl[WIHL + f * 512 + lane * 8];
        short8 bh = *(const short8*)&wl[WHHL + f * 512 + lane * 8];
        g6[g]     = MFMA16(ax[ks], bi, g6[g]);
        g6[3 + g] = MFMA16(ah[ks], bh, g6[3 + g]);
      }
    }
    int nc = 16 * u + l16;
    float brz = biasL[nc], bzz = biasL[64 + nc], bni = biasL[128 + nc], bnh = biasL[192 + nc];
    // read hp (original hid bf16) BEFORE overwriting H with h_out
    float hp[4];
    #pragma unroll
    for (int r = 0; r < 4; r++)
      hp[r] = blo(Hb[(quad * 4 + r) * 72 + nc]);
    #pragma unroll
    for (int r = 0; r < 4; r++) {
      float rg = sigm(g6[0][r] + g6[3][r] + brz);
      float zg = sigm(g6[1][r] + g6[4][r] + bzz);
      float nn = tanhp(g6[2][r] + bni + rg * (g6[5][r] + bnh));
      float ho = (1.f - zg) * nn + zg * hp[r];
      Hb[(quad * 4 + r) * 72 + nc] = (u16)pk2(ho, ho);   // h_out -> H
    }
  }

  // ---- q,k,v (frags from LDS) ----
  short8 hx[2];
  #pragma unroll
  for (int ks = 0; ks < 2; ks++)
    hx[ks] = *(const short8*)&Hb[l16 * 72 + ks * 32 + quad * 8];
  f32x4 cq[6];
  #pragma unroll
  for (int t = 0; t < 6; t++) {
    float bv = (t >= 4) ? vb[16 * (t - 4) + l16] : 0.f;
    cq[t] = (f32x4){bv, bv, bv, bv};
  }
  #pragma unroll
  for (int ks = 0; ks < 2; ks++)
    #pragma unroll
    for (int t = 0; t < 6; t++) {
      short8 b = *(const short8*)&wl[QKVL + (t * 2 + ks) * 512 + lane * 8];
      cq[t] = MFMA16(hx[ks], b, cq[t]);
    }
  #pragma unroll
  for (int t = 0; t < 4; t++)                 // q cols 0-31, k cols 32-63 (fp32)
    #pragma unroll
    for (int r = 0; r < 4; r++)
      Sf[(quad * 4 + r) * 68 + 16 * t + l16] = cq[t][r];
  #pragma unroll
  for (int t = 4; t < 6; t++)                 // v -> X cols 32-63 (bf16)
    #pragma unroll
    for (int r = 0; r < 4; r++)
      Xb[(quad * 4 + r) * 72 + 32 + 16 * (t - 4) + l16] =
          (u16)pk2(fmaxf(cq[t][r], 0.f), 0.f);

  // ---- attention (4 lanes per row, 16 rows) ----
  {
    const int r_l = lane >> 2, s4 = lane & 3;
    const int gb = r_l & ~7, ri = r_l & 7;
    const float* fq = &Sf[r_l * 68];
    float sc[2];
    #pragma unroll
    for (int jj = 0; jj < 2; jj++) {
      int j = 2 * s4 + jj;
      const float* fk = &Sf[(gb + j) * 68 + 32];
      float d = 0.f;
      #pragma unroll
      for (int a4 = 0; a4 < 32; a4 += 4) {
        float4 q4 = *(const float4*)&fq[a4];
        float4 k4 = *(const float4*)&fk[a4];
        d += q4.x * k4.x + q4.y * k4.y + q4.z * k4.z + q4.w * k4.w;
      }
      sc[jj] = (j == ri) ? -1e30f : d;
    }
    float m = fmaxf(sc[0], sc[1]);
    m = fmaxf(m, __shfl_xor(m, 1));
    m = fmaxf(m, __shfl_xor(m, 2));
    float p[2], sum = 0.f;
    #pragma unroll
    for (int jj = 0; jj < 2; jj++) {
      int j = 2 * s4 + jj;
      p[jj] = (j == ri) ? 0.f : __expf(sc[jj] - m);
      sum += p[jj];
    }
    sum += __shfl_xor(sum, 1);
    sum += __shfl_xor(sum, 2);
    float inv = 1.f / sum;
    #pragma unroll
    for (int jj = 0; jj < 2; jj++)
      Sf[r_l * 68 + 2 * s4 + jj] = p[jj] * inv;
    // PV: each lane owns cols 8*s4 .. 8*s4+7
    float xa[8];
    #pragma unroll
    for (int u = 0; u < 8; u++) xa[u] = 0.f;
    #pragma unroll
    for (int j = 0; j < 8; j++) {
      float aj = Sf[r_l * 68 + j];
      const u16* vp = &Xb[(gb + j) * 72 + 32 + 8 * s4];
      uint4 v0 = *(const uint4*)vp;
      xa[0] += aj * blo(v0.x); xa[1] += aj * bhi(v0.x);
      xa[2] += aj * blo(v0.y); xa[3] += aj * bhi(v0.y);
      xa[4] += aj * blo(v0.z); xa[5] += aj * bhi(v0.z);
      xa[6] += aj * blo(v0.w); xa[7] += aj * bhi(v0.w);
    }
    u16* xp = &Xb[r_l * 72 + 8 * s4];
    *(uint4*)xp = make_uint4(pk2(xa[0], xa[1]), pk2(xa[2], xa[3]),
                             pk2(xa[4], xa[5]), pk2(xa[6], xa[7]));
  }

  // ---- dec: [h_out | xatt] @ decW + decb ----
  {
    float db = (l16 < NACT) ? decb[l16] : 0.f;
    f32x4 co = (f32x4){db, db, db, db};
    #pragma unroll
    for (int ks = 0; ks < 2; ks++) {
      short8 b = *(const short8*)&wl[DECL + ks * 512 + lane * 8];
      short8 a = *(const short8*)&Hb[l16 * 72 + ks * 32 + quad * 8];
      co = MFMA16(a, b, co);
    }
    short8 b2 = *(const short8*)&wl[DECL + 2 * 512 + lane * 8];
    short8 a2 = *(const short8*)&Xb[l16 * 72 + quad * 8];
    co = MFMA16(a2, b2, co);
    if (l16 < NACT)
      #pragma unroll
      for (int r = 0; r < 4; r++)
        out[(size_t)(gr + quad * 4 + r) * NACT + l16] = co[r];
  }

  // ---- h_out fp32 global store (from H bf16) ----
  {
    float* outH = out + (size_t)BTOT * NACT;
    #pragma unroll
    for (int i = 0; i < 2; i++) {
      int c = lane + 64 * i, lr = c >> 3, j = c & 7;
      uint4 u = *(const uint4*)&Hb[lr * 72 + 8 * j];
      *(float4*)(outH + (size_t)(gr + lr) * 64 + 8 * j) =
          make_float4(blo(u.x), bhi(u.x), blo(u.y), bhi(u.y));
      *(float4*)(outH + (size_t)(gr + lr) * 64 + 8 * j + 4) =
          make_float4(blo(u.z), bhi(u.z), blo(u.w), bhi(u.w));
    }
  }
}

// ======================= main ================================================
__global__ __launch_bounds__(512, 2)
void commslave_main(const float* __restrict__ obs,  const float* __restrict__ hid,
                    const float* __restrict__ encb, const float* __restrict__ vb,
                    const float* __restrict__ decb, float* __restrict__ out)
{
  __shared__ __align__(16) u16 lds[LDSU16];

  const int tid  = threadIdx.x;
  const int w    = tid >> 6;
  const int lane = tid & 63;
  const int quad = lane >> 4;
  const int l16  = lane & 15;

  const int gr0 = blockIdx.x * 256 + w * 16;
  const int gr1 = gr0 + 128;

  // chunk-0 load burst FIRST (longest latency), then weight staging
  Chunk c0, c1;
  issue_loads(gr0, obs, hid, lane, quad, l16, c0);

  // ---- stage WIH/WHH/QKV/DEC frags (63 KB) + bias (1 KB) into LDS ----
  {
    uint4* dw = (uint4*)lds;
    const uint4* sw = (const uint4*)(g_wbuf + WIH0);   // 4032 uint4
    #pragma unroll
    for (int i = 0; i < 8; i++) {
      int idx = tid + 512 * i;
      if (idx < 4032) dw[idx] = sw[idx];
    }
    if (tid < 64) ((uint4*)(lds + BIASL))[tid] = ((const uint4*)g_bias)[tid];
  }
  __syncthreads();   // weights/bias visible to all waves

  u16* Xb = lds + DATA0 + w * 4608;
  const float* biasL = (const float*)(lds + BIASL);

  tile_body<false>(gr0, gr1, Xb, lds, biasL, obs, hid, encb, vb, decb, out,
                   c0, c1, lane, quad, l16);
  tile_body<true >(gr1, 0,   Xb, lds, biasL, obs, hid, encb, vb, decb, out,
                   c1, c0, lane, quad, l16);
}

extern "C" void kernel_launch(void* const* d_in, const int* in_sizes, int n_in,
                              void* d_out, int out_size, void* d_ws, size_t ws_size,
                              hipStream_t stream) {
  (void)in_sizes; (void)n_in; (void)d_ws; (void)ws_size; (void)out_size;
  const float* obs  = (const float*)d_in[0];
  const float* hid  = (const float*)d_in[1];
  const float* encW = (const float*)d_in[2];
  const float* encb = (const float*)d_in[3];
  const float* Wih  = (const float*)d_in[4];
  const float* Whh  = (const float*)d_in[5];
  const float* bih  = (const float*)d_in[6];
  const float* bhh  = (const float*)d_in[7];
  const float* qW   = (const float*)d_in[8];
  const float* kW   = (const float*)d_in[9];
  const float* vW   = (const float*)d_in[10];
  const float* vb   = (const float*)d_in[11];
  const float* decW = (const float*)d_in[12];
  const float* decb = (const float*)d_in[13];
  float* out = (float*)d_out;

  prep<<<(WTOT + 255) / 256, 256, 0, stream>>>(encW, Wih, Whh, qW, kW, vW, decW, bih, bhh);
  commslave_main<<<256, 512, 0, stream>>>(obs, hid, encb, vb, decb, out);
}